// Round 4
// baseline (946.853 us; speedup 1.0000x reference)
//
#include <hip/hip_runtime.h>
#include <cmath>

#define BATCH 64
#define NCTX 2048
#define DIM 1024
#define CHUNKS 16
#define ROWS_PER_CHUNK (NCTX / CHUNKS)     // 128
#define ROWS_PER_WAVE (ROWS_PER_CHUNK / 4) // 32
#define PAIRS (ROWS_PER_WAVE / 2)          // 16

typedef float f4_t __attribute__((ext_vector_type(4)));

// ---------------- Phase 1: flash-style scores + online softmax partials ---------------
// grid = BATCH*CHUNKS = 1024 blocks, 256 threads (4 waves). Each wave: 32 rows.
// Software-pipelined at row-pair granularity: loads for pair p+1 issue before the
// compute of pair p, keeping >=8 dwordx4 loads in flight per wave at all times.
__global__ __launch_bounds__(256, 4) void attn_phase1(
    const float* __restrict__ q,     // [B, 1, D]
    const float* __restrict__ ctx,   // [B, N, D]
    float* __restrict__ scores,      // [B, N]      (raw logits)
    float* __restrict__ part_m,      // [B, CHUNKS]
    float* __restrict__ part_l,      // [B, CHUNKS]
    float* __restrict__ part_o)      // [B, CHUNKS, D]
{
    const int blk  = blockIdx.x;
    const int b    = blk / CHUNKS;
    const int c    = blk % CHUNKS;
    const int tid  = threadIdx.x;
    const int wave = tid >> 6;
    const int lane = tid & 63;

    // q fragment: lane covers elements lane*4 + 256*j + {0..3}, j=0..3
    f4_t qf[4];
    const float* qb = q + (size_t)b * DIM;
    #pragma unroll
    for (int j = 0; j < 4; ++j)
        qf[j] = *reinterpret_cast<const f4_t*>(qb + lane * 4 + 256 * j);

    float m = -INFINITY, l = 0.f;
    f4_t o[4];
    #pragma unroll
    for (int j = 0; j < 4; ++j) o[j] = (f4_t)(0.f);

    const int row0 = c * ROWS_PER_CHUNK + wave * ROWS_PER_WAVE;
    const float* cb = ctx + (size_t)b * NCTX * DIM;
    float* sc = scores + (size_t)b * NCTX;

    f4_t cf[2][2][4];   // [buf][row-in-pair][j]

    // prologue: load pair 0 into buf 0
    #pragma unroll
    for (int r = 0; r < 2; ++r) {
        const float* cr = cb + (size_t)(row0 + r) * DIM + lane * 4;
        #pragma unroll
        for (int j = 0; j < 4; ++j)
            cf[0][r][j] = __builtin_nontemporal_load(
                reinterpret_cast<const f4_t*>(cr + 256 * j));
    }

    for (int p = 0; p < PAIRS; ++p) {
        const int buf  = p & 1;
        const int nbuf = buf ^ 1;

        // issue next pair's loads BEFORE consuming current pair
        if (p + 1 < PAIRS) {
            #pragma unroll
            for (int r = 0; r < 2; ++r) {
                const float* cr = cb + (size_t)(row0 + (p + 1) * 2 + r) * DIM + lane * 4;
                #pragma unroll
                for (int j = 0; j < 4; ++j)
                    cf[nbuf][r][j] = __builtin_nontemporal_load(
                        reinterpret_cast<const f4_t*>(cr + 256 * j));
            }
        }

        // dots for the current pair
        float s0, s1;
        {
            float a0 = qf[0].x * cf[buf][0][0].x + qf[0].y * cf[buf][0][0].y
                     + qf[0].z * cf[buf][0][0].z + qf[0].w * cf[buf][0][0].w;
            float a1 = qf[1].x * cf[buf][0][1].x + qf[1].y * cf[buf][0][1].y
                     + qf[1].z * cf[buf][0][1].z + qf[1].w * cf[buf][0][1].w;
            float a2 = qf[2].x * cf[buf][0][2].x + qf[2].y * cf[buf][0][2].y
                     + qf[2].z * cf[buf][0][2].z + qf[2].w * cf[buf][0][2].w;
            float a3 = qf[3].x * cf[buf][0][3].x + qf[3].y * cf[buf][0][3].y
                     + qf[3].z * cf[buf][0][3].z + qf[3].w * cf[buf][0][3].w;
            s0 = (a0 + a1) + (a2 + a3);
            float b0 = qf[0].x * cf[buf][1][0].x + qf[0].y * cf[buf][1][0].y
                     + qf[0].z * cf[buf][1][0].z + qf[0].w * cf[buf][1][0].w;
            float b1 = qf[1].x * cf[buf][1][1].x + qf[1].y * cf[buf][1][1].y
                     + qf[1].z * cf[buf][1][1].z + qf[1].w * cf[buf][1][1].w;
            float b2 = qf[2].x * cf[buf][1][2].x + qf[2].y * cf[buf][1][2].y
                     + qf[2].z * cf[buf][1][2].z + qf[2].w * cf[buf][1][2].w;
            float b3 = qf[3].x * cf[buf][1][3].x + qf[3].y * cf[buf][1][3].y
                     + qf[3].z * cf[buf][1][3].z + qf[3].w * cf[buf][1][3].w;
            s1 = (b0 + b1) + (b2 + b3);
        }

        // two independent 64-lane butterflies
        #pragma unroll
        for (int off = 32; off >= 1; off >>= 1) {
            s0 += __shfl_xor(s0, off, 64);
            s1 += __shfl_xor(s1, off, 64);
        }

        // branchless online softmax (exp(-inf)=0 covers the first iteration)
        const float m_new = fmaxf(m, fmaxf(s0, s1));
        const float a     = __expf(m - m_new);
        const float p0    = __expf(s0 - m_new);
        const float p1    = __expf(s1 - m_new);
        l = l * a + p0 + p1;
        #pragma unroll
        for (int j = 0; j < 4; ++j) {
            o[j].x = o[j].x * a + p0 * cf[buf][0][j].x + p1 * cf[buf][1][j].x;
            o[j].y = o[j].y * a + p0 * cf[buf][0][j].y + p1 * cf[buf][1][j].y;
            o[j].z = o[j].z * a + p0 * cf[buf][0][j].z + p1 * cf[buf][1][j].z;
            o[j].w = o[j].w * a + p0 * cf[buf][0][j].w + p1 * cf[buf][1][j].w;
        }
        m = m_new;

        if (lane < 2) sc[row0 + p * 2 + lane] = lane ? s1 : s0;
    }

    // ---- combine the 4 waves of this block ----
    __shared__ float wm[4], wl[4];
    __shared__ float o_lds[4 * DIM];
    if (lane == 0) { wm[wave] = m; wl[wave] = l; }
    __syncthreads();

    const float Mb = fmaxf(fmaxf(wm[0], wm[1]), fmaxf(wm[2], wm[3]));
    float Lb = 0.f;
    #pragma unroll
    for (int w = 0; w < 4; ++w) Lb += wl[w] * __expf(wm[w] - Mb);

    const float aw = __expf(m - Mb);
    #pragma unroll
    for (int j = 0; j < 4; ++j) {
        f4_t t = o[j] * aw;
        *reinterpret_cast<f4_t*>(&o_lds[wave * DIM + lane * 4 + 256 * j]) = t;
    }
    __syncthreads();

    {
        const int e = tid * 4;
        f4_t s0 = *reinterpret_cast<const f4_t*>(&o_lds[0 * DIM + e]);
        f4_t s1 = *reinterpret_cast<const f4_t*>(&o_lds[1 * DIM + e]);
        f4_t s2 = *reinterpret_cast<const f4_t*>(&o_lds[2 * DIM + e]);
        f4_t s3 = *reinterpret_cast<const f4_t*>(&o_lds[3 * DIM + e]);
        f4_t r = (s0 + s1) + (s2 + s3);
        *reinterpret_cast<f4_t*>(&part_o[((size_t)b * CHUNKS + c) * DIM + e]) = r;
    }
    if (tid == 0) {
        part_m[b * CHUNKS + c] = Mb;
        part_l[b * CHUNKS + c] = Lb;
    }
}

// ---------------- Phase 2: combine chunk partials -> mix; write attn -----------------
// grid = BATCH*4 = 256 blocks, 256 threads. Each block: D/4 mix elems + N/4 attn elems.
__global__ __launch_bounds__(256) void attn_phase2(
    const float* __restrict__ scores,
    const float* __restrict__ part_m,
    const float* __restrict__ part_l,
    const float* __restrict__ part_o,
    float* __restrict__ mix,        // [B, D] workspace
    float* __restrict__ attn_out)   // d_out + B*D, [B, N]
{
    const int b    = blockIdx.x >> 2;
    const int part = blockIdx.x & 3;
    const int tid  = threadIdx.x;

    float M = -INFINITY;
    #pragma unroll
    for (int i = 0; i < CHUNKS; ++i) M = fmaxf(M, part_m[b * CHUNKS + i]);

    float w[CHUNKS];
    float L = 0.f;
    #pragma unroll
    for (int i = 0; i < CHUNKS; ++i) {
        w[i] = __expf(part_m[b * CHUNKS + i] - M);
        L += part_l[b * CHUNKS + i] * w[i];
    }
    const float invL = 1.f / L;

    // mix slice: 256 consecutive elements
    {
        const int e = part * 256 + tid;
        float acc = 0.f;
        #pragma unroll
        for (int i = 0; i < CHUNKS; ++i)
            acc += part_o[((size_t)b * CHUNKS + i) * DIM + e] * w[i];
        mix[(size_t)b * DIM + e] = acc * invL;
    }

    // attn slice: 512 consecutive elements
    #pragma unroll
    for (int t = 0; t < 2; ++t) {
        const int n = part * 512 + t * 256 + tid;
        attn_out[(size_t)b * NCTX + n] =
            __expf(scores[(size_t)b * NCTX + n] - M) * invL;
    }
}

// ---------------- Phase 3: out = tanh([mix, q] @ W^T + bias) --------------------------
// grid = (D/32) * (B/4) = 512 blocks, 256 threads. LDS: combined[4][2048] = 32 KB.
#define BT 4
#define DT 32
__global__ __launch_bounds__(256) void attn_phase3(
    const float* __restrict__ mix,   // [B, D]
    const float* __restrict__ q,     // [B, 1, D]
    const float* __restrict__ W,     // [D, 2D]
    const float* __restrict__ bias,  // [D]
    float* __restrict__ out)         // d_out, [B, D]
{
    const int d_chunk = blockIdx.x % (DIM / DT);
    const int b_chunk = blockIdx.x / (DIM / DT);
    const int d0 = d_chunk * DT;
    const int b0 = b_chunk * BT;
    const int tid  = threadIdx.x;
    const int wave = tid >> 6;
    const int lane = tid & 63;

    __shared__ float comb[BT * 2 * DIM];   // 4 * 2048 floats = 32 KB
    for (int i = tid; i < BT * 2 * DIM; i += 256) {
        const int bl = i >> 11;          // / 2048
        const int e  = i & 2047;
        comb[i] = (e < DIM) ? mix[(size_t)(b0 + bl) * DIM + e]
                            : q[(size_t)(b0 + bl) * DIM + (e - DIM)];
    }
    __syncthreads();

    const int d_base = d0 + wave * (DT / 4);   // 8 d's per wave
    #pragma unroll
    for (int g = 0; g < 2; ++g) {
        const int dg = d_base + g * 4;
        float acc[4][BT];
        #pragma unroll
        for (int di = 0; di < 4; ++di)
            #pragma unroll
            for (int bl = 0; bl < BT; ++bl) acc[di][bl] = 0.f;

        for (int kk = 0; kk < 2 * DIM; kk += 256) {
            f4_t wv[4];
            #pragma unroll
            for (int di = 0; di < 4; ++di)
                wv[di] = *reinterpret_cast<const f4_t*>(
                    W + (size_t)(dg + di) * (2 * DIM) + kk + lane * 4);
            #pragma unroll
            for (int bl = 0; bl < BT; ++bl) {
                f4_t cv = *reinterpret_cast<const f4_t*>(
                    &comb[bl * 2 * DIM + kk + lane * 4]);
                #pragma unroll
                for (int di = 0; di < 4; ++di) {
                    acc[di][bl] += wv[di].x * cv.x;
                    acc[di][bl] += wv[di].y * cv.y;
                    acc[di][bl] += wv[di].z * cv.z;
                    acc[di][bl] += wv[di].w * cv.w;
                }
            }
        }

        float myval = 0.f;
        #pragma unroll
        for (int di = 0; di < 4; ++di) {
            #pragma unroll
            for (int bl = 0; bl < BT; ++bl) {
                float v = acc[di][bl];
                #pragma unroll
                for (int off = 32; off >= 1; off >>= 1)
                    v += __shfl_xor(v, off, 64);
                if (lane == di * BT + bl) myval = v;
            }
        }
        if (lane < 16) {
            const int di = lane >> 2;
            const int bl = lane & 3;
            const int d  = dg + di;
            out[(size_t)(b0 + bl) * DIM + d] = tanhf(myval + bias[d]);
        }
    }
}

extern "C" void kernel_launch(void* const* d_in, const int* in_sizes, int n_in,
                              void* d_out, int out_size, void* d_ws, size_t ws_size,
                              hipStream_t stream) {
    const float* q    = (const float*)d_in[0];   // output, [B,1,D]
    const float* ctx  = (const float*)d_in[1];   // context, [B,N,D]
    const float* W    = (const float*)d_in[2];   // W_out, [D, 2D]
    const float* bias = (const float*)d_in[3];   // b_out, [D]

    float* out_main = (float*)d_out;                         // [B, D]
    float* attn_out = (float*)d_out + (size_t)BATCH * DIM;   // [B, N]

    // workspace layout (floats): scores | part_m | part_l | part_o | mix  (~5 MB)
    float* ws      = (float*)d_ws;
    float* scores  = ws;                                    // B*N       = 131072
    float* part_m  = scores + (size_t)BATCH * NCTX;         // B*CHUNKS  = 1024
    float* part_l  = part_m + BATCH * CHUNKS;               // 1024
    float* part_o  = part_l + BATCH * CHUNKS;               // B*CHUNKS*D = 1048576
    float* mix     = part_o + (size_t)BATCH * CHUNKS * DIM; // B*D = 65536

    attn_phase1<<<BATCH * CHUNKS, 256, 0, stream>>>(q, ctx, scores,
                                                    part_m, part_l, part_o);
    attn_phase2<<<BATCH * 4, 256, 0, stream>>>(scores, part_m, part_l, part_o,
                                               mix, attn_out);
    attn_phase3<<<(DIM / DT) * (BATCH / BT), 256, 0, stream>>>(mix, q, W, bias,
                                                               out_main);
}